// Round 4
// baseline (529.835 us; speedup 1.0000x reference)
//
#include <hip/hip_runtime.h>
#include <math.h>

// Dims (CLEVR-scale, fixed)
#define BB 128
#define NN 36
#define DF 512
#define DE 256
#define DV 512
#define HH 256
#define NCC 28
#define LQ 5
#define NE 1296           // N*N edges per batch
#define SCALE 0.04419417382415922f   // 1/sqrt(512)

typedef __bf16 bf16_8 __attribute__((ext_vector_type(8)));
typedef __bf16 bf16_4 __attribute__((ext_vector_type(4)));
typedef float  f32_4  __attribute__((ext_vector_type(4)));

__device__ __forceinline__ float sigmoidf_(float x){ return 1.0f/(1.0f + expf(-x)); }
__device__ __forceinline__ float reluf_(float x){ return x > 0.f ? x : 0.f; }

__device__ __forceinline__ bf16_8 cvt8(f32_4 f0, f32_4 f1){
    bf16_8 v;
    #pragma unroll
    for (int i=0;i<4;i++){ v[i] = (__bf16)f0[i]; v[i+4] = (__bf16)f1[i]; }
    return v;
}
// hi/lo split of 8 fp32 into two bf16_8 (3-term split-bf16 emulation, ~2^-18 rel err)
__device__ __forceinline__ void split8(f32_4 f0, f32_4 f1, bf16_8& h, bf16_8& l){
    #pragma unroll
    for (int i=0;i<4;i++){
        __bf16 hi = (__bf16)f0[i];
        h[i] = hi; l[i] = (__bf16)(f0[i] - (float)hi);
        __bf16 hi2 = (__bf16)f1[i];
        h[i+4] = hi2; l[i+4] = (__bf16)(f1[i] - (float)hi2);
    }
}

// ---------------------------------------------------------------------------
// Pack all weight matrices into MFMA B-fragment planes.
// For [K x N] row-major W: packed[(slot*64+lane)*8+j] = W[(kt*32+(lane>>4)*8+j)*ldw + nt*16+(lane&15)]
// with slot = kt*(N/16)+nt. hi = bf16(w); lo = bf16(w-hi).
// Blocks: [0,64) W_n1(512x256) | [64,128) W_n2(256x512) | [128,256) W_q(512x512)
//         [256,320) W_c1(512x256) | [320,352) W_e1(256x256, hi only)
//         [352,356) W_c2(256x28 -> padded N=32)
// ---------------------------------------------------------------------------
__global__ __launch_bounds__(256) void k_pack_all(
    const float* __restrict__ W_n1, const float* __restrict__ W_n2,
    const float* __restrict__ W_q,  const float* __restrict__ W_c1,
    const float* __restrict__ W_e1, const float* __restrict__ W_c2,
    __bf16* __restrict__ Pn1h, __bf16* __restrict__ Pn1l,
    __bf16* __restrict__ Pn2h, __bf16* __restrict__ Pn2l,
    __bf16* __restrict__ Pqh,  __bf16* __restrict__ Pql,
    __bf16* __restrict__ Pc1h, __bf16* __restrict__ Pc1l,
    __bf16* __restrict__ Peh,
    __bf16* __restrict__ Pc2h, __bf16* __restrict__ Pc2l)
{
    int bid = blockIdx.x;
    const float* W; __bf16 *Ph, *Pl; int N, base, realN;
    if (bid < 64)       { W=W_n1; Ph=Pn1h; Pl=Pn1l; N=256; base=0;   realN=256; }
    else if (bid < 128) { W=W_n2; Ph=Pn2h; Pl=Pn2l; N=512; base=64;  realN=512; }
    else if (bid < 256) { W=W_q;  Ph=Pqh;  Pl=Pql;  N=512; base=128; realN=512; }
    else if (bid < 320) { W=W_c1; Ph=Pc1h; Pl=Pc1l; N=256; base=256; realN=256; }
    else if (bid < 352) { W=W_e1; Ph=Peh;  Pl=nullptr; N=256; base=320; realN=256; }
    else                { W=W_c2; Ph=Pc2h; Pl=Pc2l; N=32;  base=352; realN=28;  }
    int g = (bid-base)*256 + threadIdx.x;
    int lane = g & 63, slot = g >> 6;
    int NT = N >> 4;
    int nt = slot % NT, kt = slot / NT;
    int krow = kt*32 + (lane>>4)*8, ncol = nt*16 + (lane&15);
    #pragma unroll
    for (int j=0;j<8;j++){
        float w = (ncol < realN) ? W[(size_t)(krow+j)*realN + ncol] : 0.f;
        __bf16 hi = (__bf16)w;
        Ph[(size_t)g*8+j] = hi;
        if (Pl) Pl[(size_t)g*8+j] = (__bf16)(w - (float)hi);
    }
}

// ---------------------------------------------------------------------------
// K1: per-batch: gather q0..q3; ve[b][h] = W_e2[h,:]·q2 (wave-coalesced); se[b]=b_e2·q2
// ---------------------------------------------------------------------------
__global__ __launch_bounds__(256) void k_prep(
    const float* __restrict__ word_emb, const int* __restrict__ program_inputs,
    const float* __restrict__ W_e2, const float* __restrict__ b_e2,
    float* __restrict__ qws, float* __restrict__ ve, float* __restrict__ se)
{
    int b = blockIdx.x, t = threadIdx.x, wv = t>>6, lane = t&63;
    int idx[4];
    #pragma unroll
    for (int k=0;k<4;k++) idx[k] = program_inputs[b*LQ + k];
    #pragma unroll
    for (int k=0;k<4;k++){
        qws[((size_t)(b*4+k))*DV + t]       = word_emb[(size_t)idx[k]*DV + t];
        qws[((size_t)(b*4+k))*DV + t + 256] = word_emb[(size_t)idx[k]*DV + t + 256];
    }
    const float* q2p = word_emb + (size_t)idx[2]*DV + lane*8;
    f32_4 qa = *(const f32_4*)q2p, qb = *(const f32_4*)(q2p+4);
    for (int i=0;i<64;i++){
        int h = wv*64 + i;
        const float* wr = W_e2 + (size_t)h*DV + lane*8;
        f32_4 a = *(const f32_4*)wr, c = *(const f32_4*)(wr+4);
        float p = a[0]*qa[0] + a[1]*qa[1] + a[2]*qa[2] + a[3]*qa[3]
                + c[0]*qb[0] + c[1]*qb[1] + c[2]*qb[2] + c[3]*qb[3];
        #pragma unroll
        for (int off=32; off; off>>=1) p += __shfl_xor(p, off, 64);
        if (lane==0) ve[b*HH + h] = p;
    }
    float pp = b_e2[t]*word_emb[(size_t)idx[2]*DV + t]
             + b_e2[t+256]*word_emb[(size_t)idx[2]*DV + t + 256];
    __shared__ float red[4];
    #pragma unroll
    for (int off=32; off; off>>=1) pp += __shfl_down(pp, off, 64);
    if ((t&63)==0) red[t>>6] = pp;
    __syncthreads();
    if (t==0) se[b] = red[0]+red[1]+red[2]+red[3];
}

// ---------------------------------------------------------------------------
// K2: fused node MLP: nf = relu(X@W1+b1)@W2+b2. 16 rows/block, 288 blocks.
// GEMM1 A-fragments loaded DIRECTLY from global (frag layout matches rows on
// lane&15, k-chunk on lane>>4: 16x128B segments per instr, coalesced). Hid
// round-trips LDS (C-layout -> A-layout needs cross-lane).
// ---------------------------------------------------------------------------
__global__ __launch_bounds__(256) void k_node(
    const float* __restrict__ X,
    const __bf16* __restrict__ W1h, const __bf16* __restrict__ W1l,
    const float* __restrict__ b1,
    const __bf16* __restrict__ W2h, const __bf16* __restrict__ W2l,
    const float* __restrict__ b2,
    float* __restrict__ nf)
{
    __shared__ __align__(16) __bf16 hh[4096];   // 8 KB, frag layout K=256
    __shared__ __align__(16) __bf16 hl[4096];   // 8 KB
    int r0 = blockIdx.x*16, t = threadIdx.x, wv = t>>6, lane = t&63;
    int m = lane&15, kc = lane>>4;
    int q = lane>>4, c = lane&15;

    // GEMM1: hid[16x256] = relu(X @ W1 + b1). Wave wv: cols wv*64..+63.
    const float* xr = X + (size_t)(r0+m)*DF + kc*8;
    f32_4 zero = {0.f,0.f,0.f,0.f};
    f32_4 acc1[4];
    #pragma unroll
    for (int nt=0;nt<4;nt++) acc1[nt] = zero;
    for (int kt=0; kt<16; kt++){
        f32_4 f0 = *(const f32_4*)(xr + kt*32);
        f32_4 f1 = *(const f32_4*)(xr + kt*32 + 4);
        bf16_8 ah, al;
        split8(f0, f1, ah, al);
        #pragma unroll
        for (int nt=0;nt<4;nt++){
            size_t bo = ((size_t)(kt*16 + wv*4+nt)*64 + lane)*8;
            bf16_8 bh = *(const bf16_8*)(W1h + bo);
            bf16_8 bl = *(const bf16_8*)(W1l + bo);
            acc1[nt] = __builtin_amdgcn_mfma_f32_16x16x32_bf16(ah, bh, acc1[nt], 0,0,0);
            acc1[nt] = __builtin_amdgcn_mfma_f32_16x16x32_bf16(al, bh, acc1[nt], 0,0,0);
            acc1[nt] = __builtin_amdgcn_mfma_f32_16x16x32_bf16(ah, bl, acc1[nt], 0,0,0);
        }
    }
    // epilogue1: relu(+b1), hi/lo -> hid frag layout (K=256)
    #pragma unroll
    for (int nt=0;nt<4;nt++){
        int col = wv*64 + nt*16 + c;
        float bias = b1[col];
        int kt2 = col>>5, j2 = col&7;
        int lbase = ((col&31)>>3)*16;
        #pragma unroll
        for (int r=0;r<4;r++){
            int row = q*4 + r;
            float v = reluf_(acc1[nt][r] + bias);
            __bf16 hi = (__bf16)v;
            int off = (kt2*64 + lbase + row)*8 + j2;
            hh[off] = hi;
            hl[off] = (__bf16)(v - (float)hi);
        }
    }
    __syncthreads();

    // GEMM2: nf[16x512] = hid @ W2 + b2. Wave wv: cols wv*128..+127.
    f32_4 acc2[8];
    #pragma unroll
    for (int nt=0;nt<8;nt++) acc2[nt] = zero;
    for (int kt=0; kt<8; kt++){
        bf16_8 ah = *(const bf16_8*)&hh[(kt*64+lane)*8];
        bf16_8 al = *(const bf16_8*)&hl[(kt*64+lane)*8];
        #pragma unroll
        for (int nt=0;nt<8;nt++){
            size_t bo = ((size_t)(kt*32 + wv*8+nt)*64 + lane)*8;
            bf16_8 bh = *(const bf16_8*)(W2h + bo);
            bf16_8 bl = *(const bf16_8*)(W2l + bo);
            acc2[nt] = __builtin_amdgcn_mfma_f32_16x16x32_bf16(ah, bh, acc2[nt], 0,0,0);
            acc2[nt] = __builtin_amdgcn_mfma_f32_16x16x32_bf16(al, bh, acc2[nt], 0,0,0);
            acc2[nt] = __builtin_amdgcn_mfma_f32_16x16x32_bf16(ah, bl, acc2[nt], 0,0,0);
        }
    }
    #pragma unroll
    for (int nt=0;nt<8;nt++){
        int col = wv*128 + nt*16 + c;
        float bias = b2[col];
        #pragma unroll
        for (int r=0;r<4;r++){
            int row = q*4 + r;
            nf[(size_t)(r0+row)*DV + col] = acc2[nt][r] + bias;
        }
    }
}

// ---------------------------------------------------------------------------
// K4: edge kernel v3. 48 edges/block. NO LDS staging: each lane loads its A
// fragments directly from global (nontemporal; 16x128B segments/instr) and
// converts fp32->bf16 in registers. LDS only for the 768B reduction buffer.
// ---------------------------------------------------------------------------
__global__ __launch_bounds__(256) void k_edge(
    const float* __restrict__ E, const __bf16* __restrict__ Wp,
    const float* __restrict__ b_e1, const float* __restrict__ ve,
    const float* __restrict__ se, float* __restrict__ weit)
{
    __shared__ float red[4][48];
    int bx = blockIdx.x;
    int b = bx / 27, tile = bx % 27;
    int e0 = tile*48;
    int t = threadIdx.x, wv = t>>6, lane = t&63;
    int m = lane&15, kc = lane>>4;
    const float* base = E + ((size_t)b*NE + e0)*DE + kc*8;
    const float* rp0 = base + (size_t)(0*16 + m)*DE;
    const float* rp1 = base + (size_t)(1*16 + m)*DE;
    const float* rp2 = base + (size_t)(2*16 + m)*DE;

    f32_4 zero = {0.f,0.f,0.f,0.f};
    f32_4 acc[3][4];
    #pragma unroll
    for (int mt=0;mt<3;mt++)
        #pragma unroll
        for (int nt=0;nt<4;nt++) acc[mt][nt] = zero;

    for (int kt=0; kt<8; kt++){
        bf16_8 af[3];
        af[0] = cvt8(__builtin_nontemporal_load((const f32_4*)(rp0 + kt*32)),
                     __builtin_nontemporal_load((const f32_4*)(rp0 + kt*32 + 4)));
        af[1] = cvt8(__builtin_nontemporal_load((const f32_4*)(rp1 + kt*32)),
                     __builtin_nontemporal_load((const f32_4*)(rp1 + kt*32 + 4)));
        af[2] = cvt8(__builtin_nontemporal_load((const f32_4*)(rp2 + kt*32)),
                     __builtin_nontemporal_load((const f32_4*)(rp2 + kt*32 + 4)));
        #pragma unroll
        for (int nt=0;nt<4;nt++){
            bf16_8 bfrag = *(const bf16_8*)(Wp + ((size_t)(kt*16 + (wv*4+nt))*64 + lane)*8);
            #pragma unroll
            for (int mt=0;mt<3;mt++)
                acc[mt][nt] = __builtin_amdgcn_mfma_f32_16x16x32_bf16(af[mt], bfrag, acc[mt][nt], 0,0,0);
        }
    }

    // epilogue: relu(+bias), dot with ve over this wave's 64 n-cols, reduce
    float ves[4], be[4];
    #pragma unroll
    for (int nt=0;nt<4;nt++){
        int n = wv*64 + nt*16 + m;
        ves[nt] = ve[b*HH + n];
        be[nt]  = b_e1[n];
    }
    float part[3][4];
    #pragma unroll
    for (int mt=0;mt<3;mt++)
        #pragma unroll
        for (int r=0;r<4;r++){
            float s = 0.f;
            #pragma unroll
            for (int nt=0;nt<4;nt++)
                s = fmaf(reluf_(acc[mt][nt][r] + be[nt]), ves[nt], s);
            part[mt][r] = s;
        }
    #pragma unroll
    for (int off=1; off<16; off<<=1)
        #pragma unroll
        for (int mt=0;mt<3;mt++)
            #pragma unroll
            for (int r=0;r<4;r++)
                part[mt][r] += __shfl_xor(part[mt][r], off, 64);
    if (m==0){
        int g = lane>>4;
        #pragma unroll
        for (int mt=0;mt<3;mt++)
            #pragma unroll
            for (int r=0;r<4;r++)
                red[wv][mt*16 + g*4 + r] = part[mt][r];
    }
    __syncthreads();
    if (t < 48){
        float logit = red[0][t]+red[1][t]+red[2][t]+red[3][t] + se[b];
        weit[(size_t)b*NE + e0 + t] = sigmoidf_(logit * SCALE);
    }
}

// ---------------------------------------------------------------------------
// K5a: per-batch attention chain -> x = (pooled * q0) into xws [B,DV]
// ---------------------------------------------------------------------------
__global__ __launch_bounds__(256) void k_attn(
    const float* __restrict__ nf, const float* __restrict__ qws,
    const float* __restrict__ weit, float* __restrict__ xws)
{
    int b = blockIdx.x, t = threadIdx.x;
    int wv = t>>6, lane = t&63;
    __shared__ float a1[NN], a2[NN], a3[NN];
    __shared__ float denom;
    const float* nfb = nf + (size_t)b*NN*DV;
    const float* q0 = qws + ((size_t)(b*4+0))*DV;
    const float* q1 = qws + ((size_t)(b*4+1))*DV;
    const float* q3 = qws + ((size_t)(b*4+3))*DV;

    for (int i=wv; i<NN; i+=4){
        const float* row = nfb + (size_t)i*DV + lane*8;
        const float* qq  = q3 + lane*8;
        f32_4 x0 = *(const f32_4*)row, x1 = *(const f32_4*)(row+4);
        f32_4 y0 = *(const f32_4*)qq,  y1 = *(const f32_4*)(qq+4);
        float p = x0[0]*y0[0] + x0[1]*y0[1] + x0[2]*y0[2] + x0[3]*y0[3]
                + x1[0]*y1[0] + x1[1]*y1[1] + x1[2]*y1[2] + x1[3]*y1[3];
        #pragma unroll
        for (int off=32; off; off>>=1) p += __shfl_xor(p, off, 64);
        if (lane==0) a1[i] = sigmoidf_(p*SCALE);
    }
    __syncthreads();
    if (t < NN){
        const float* wrow = weit + (size_t)b*NE;
        float s = 0.f;
        for (int i=0;i<NN;i++) s = fmaf(a1[i], wrow[i*NN + t], s);
        a2[t] = fminf(fmaxf(s, 0.f), 1.f);
    }
    __syncthreads();
    for (int i=wv; i<NN; i+=4){
        const float* row = nfb + (size_t)i*DV + lane*8;
        const float* qq  = q1 + lane*8;
        f32_4 x0 = *(const f32_4*)row, x1 = *(const f32_4*)(row+4);
        f32_4 y0 = *(const f32_4*)qq,  y1 = *(const f32_4*)(qq+4);
        float p = x0[0]*y0[0] + x0[1]*y0[1] + x0[2]*y0[2] + x0[3]*y0[3]
                + x1[0]*y1[0] + x1[1]*y1[1] + x1[2]*y1[2] + x1[3]*y1[3];
        #pragma unroll
        for (int off=32; off; off>>=1) p += __shfl_xor(p, off, 64);
        if (lane==0) a3[i] = a2[i]*sigmoidf_(p*SCALE);
    }
    __syncthreads();
    if (t==0){
        float s = 0.f;
        for (int i=0;i<NN;i++) s += a3[i];
        denom = 1.f/(s + 1e-8f);
    }
    __syncthreads();
    float p0=0.f, p1=0.f;
    for (int i=0;i<NN;i++){
        float a = a3[i]*denom;
        p0 = fmaf(a, nfb[(size_t)i*DV + t], p0);
        p1 = fmaf(a, nfb[(size_t)i*DV + t + 256], p1);
    }
    xws[(size_t)b*DV + t]       = p0*q0[t];
    xws[(size_t)b*DV + t + 256] = p1*q0[t+256];
}

// ---------------------------------------------------------------------------
// K5b: head chain: out = relu(relu(x@W_q+b_q)@W_c1+b_c1)@W_c2+b_c2
// 8 blocks x 16 rows. GEMM1 A direct from global; GEMM3 via MFMA (W_c2 packed
// to N=32). 48 KB LDS.
// ---------------------------------------------------------------------------
__global__ __launch_bounds__(256) void k_head(
    const float* __restrict__ xws,
    const __bf16* __restrict__ Wqh, const __bf16* __restrict__ Wql,
    const float* __restrict__ b_q,
    const __bf16* __restrict__ Wc1h, const __bf16* __restrict__ Wc1l,
    const float* __restrict__ b_c1,
    const __bf16* __restrict__ Pc2h, const __bf16* __restrict__ Pc2l,
    const float* __restrict__ b_c2,
    float* __restrict__ out)
{
    __shared__ __align__(16) __bf16 oh[8192];   // 16 KB, o frag K=512
    __shared__ __align__(16) __bf16 ol[8192];   // 16 KB
    __shared__ __align__(16) __bf16 hfh[4096];  // 8 KB, h frag K=256
    __shared__ __align__(16) __bf16 hfl[4096];  // 8 KB

    int r0 = blockIdx.x*16, t = threadIdx.x, wv = t>>6, lane = t&63;
    int m = lane&15, kc = lane>>4;
    int q = lane>>4, c = lane&15;
    f32_4 zero = {0.f,0.f,0.f,0.f};

    // GEMM1: o[16x512] = relu(x @ W_q + b_q). A direct from global.
    const float* xr = xws + (size_t)(r0+m)*DV + kc*8;
    f32_4 acc[8];
    #pragma unroll
    for (int nt=0;nt<8;nt++) acc[nt] = zero;
    for (int kt=0; kt<16; kt++){
        f32_4 f0 = *(const f32_4*)(xr + kt*32);
        f32_4 f1 = *(const f32_4*)(xr + kt*32 + 4);
        bf16_8 ah, al;
        split8(f0, f1, ah, al);
        #pragma unroll
        for (int nt=0;nt<8;nt++){
            size_t bo = ((size_t)(kt*32 + wv*8+nt)*64 + lane)*8;
            bf16_8 bh = *(const bf16_8*)(Wqh + bo);
            bf16_8 bl = *(const bf16_8*)(Wql + bo);
            acc[nt] = __builtin_amdgcn_mfma_f32_16x16x32_bf16(ah, bh, acc[nt], 0,0,0);
            acc[nt] = __builtin_amdgcn_mfma_f32_16x16x32_bf16(al, bh, acc[nt], 0,0,0);
            acc[nt] = __builtin_amdgcn_mfma_f32_16x16x32_bf16(ah, bl, acc[nt], 0,0,0);
        }
    }
    #pragma unroll
    for (int nt=0;nt<8;nt++){
        int col = wv*128 + nt*16 + c;
        float bias = b_q[col];
        int kt2 = col>>5, j2 = col&7;
        int lbase = ((col&31)>>3)*16;
        #pragma unroll
        for (int r=0;r<4;r++){
            int row = q*4 + r;
            float v = reluf_(acc[nt][r] + bias);
            __bf16 hi = (__bf16)v;
            int off = (kt2*64 + lbase + row)*8 + j2;
            oh[off] = hi;
            ol[off] = (__bf16)(v - (float)hi);
        }
    }
    __syncthreads();

    // GEMM2: h[16x256] = relu(o @ W_c1 + b_c1). Wave: 64 cols.
    f32_4 acc2[4];
    #pragma unroll
    for (int nt=0;nt<4;nt++) acc2[nt] = zero;
    for (int kt=0; kt<16; kt++){
        bf16_8 ah = *(const bf16_8*)&oh[(kt*64+lane)*8];
        bf16_8 al = *(const bf16_8*)&ol[(kt*64+lane)*8];
        #pragma unroll
        for (int nt=0;nt<4;nt++){
            size_t bo = ((size_t)(kt*16 + wv*4+nt)*64 + lane)*8;
            bf16_8 bh = *(const bf16_8*)(Wc1h + bo);
            bf16_8 bl = *(const bf16_8*)(Wc1l + bo);
            acc2[nt] = __builtin_amdgcn_mfma_f32_16x16x32_bf16(ah, bh, acc2[nt], 0,0,0);
            acc2[nt] = __builtin_amdgcn_mfma_f32_16x16x32_bf16(al, bh, acc2[nt], 0,0,0);
            acc2[nt] = __builtin_amdgcn_mfma_f32_16x16x32_bf16(ah, bl, acc2[nt], 0,0,0);
        }
    }
    // epilogue2: relu(+b_c1) -> h frag layout (K=256), hi/lo
    #pragma unroll
    for (int nt=0;nt<4;nt++){
        int col = wv*64 + nt*16 + c;
        float bias = b_c1[col];
        int kt2 = col>>5, j2 = col&7;
        int lbase = ((col&31)>>3)*16;
        #pragma unroll
        for (int r=0;r<4;r++){
            int row = q*4 + r;
            float v = reluf_(acc2[nt][r] + bias);
            __bf16 hi = (__bf16)v;
            int off = (kt2*64 + lbase + row)*8 + j2;
            hfh[off] = hi;
            hfl[off] = (__bf16)(v - (float)hi);
        }
    }
    __syncthreads();

    // GEMM3: out[16x28] = h @ W_c2 + b_c2 via MFMA (N padded to 32).
    // Waves 0,1 each own one 16-col n-tile.
    if (wv < 2){
        f32_4 acc3 = zero;
        for (int kt=0; kt<8; kt++){
            bf16_8 ah = *(const bf16_8*)&hfh[(kt*64+lane)*8];
            bf16_8 al = *(const bf16_8*)&hfl[(kt*64+lane)*8];
            size_t bo = ((size_t)(kt*2 + wv)*64 + lane)*8;
            bf16_8 bh = *(const bf16_8*)(Pc2h + bo);
            bf16_8 bl = *(const bf16_8*)(Pc2l + bo);
            acc3 = __builtin_amdgcn_mfma_f32_16x16x32_bf16(ah, bh, acc3, 0,0,0);
            acc3 = __builtin_amdgcn_mfma_f32_16x16x32_bf16(al, bh, acc3, 0,0,0);
            acc3 = __builtin_amdgcn_mfma_f32_16x16x32_bf16(ah, bl, acc3, 0,0,0);
        }
        int col = wv*16 + c;
        if (col < NCC){
            float bias = b_c2[col];
            #pragma unroll
            for (int r=0;r<4;r++){
                int row = q*4 + r;
                out[(size_t)(r0+row)*NCC + col] = acc3[r] + bias;
            }
        }
    }
}

// ---------------------------------------------------------------------------
extern "C" void kernel_launch(void* const* d_in, const int* in_sizes, int n_in,
                              void* d_out, int out_size, void* d_ws, size_t ws_size,
                              hipStream_t stream)
{
    const float* node_feats = (const float*)d_in[0];
    const float* edge_feats = (const float*)d_in[1];
    const float* W_n1 = (const float*)d_in[2];
    const float* b_n1 = (const float*)d_in[3];
    const float* W_n2 = (const float*)d_in[4];
    const float* b_n2 = (const float*)d_in[5];
    const float* W_e1 = (const float*)d_in[6];
    const float* b_e1 = (const float*)d_in[7];
    const float* W_e2 = (const float*)d_in[8];
    const float* b_e2 = (const float*)d_in[9];
    const float* W_q  = (const float*)d_in[10];
    const float* b_q  = (const float*)d_in[11];
    const float* W_c1 = (const float*)d_in[12];
    const float* b_c1 = (const float*)d_in[13];
    const float* W_c2 = (const float*)d_in[14];
    const float* b_c2 = (const float*)d_in[15];
    const float* word_emb = (const float*)d_in[16];
    const int* program_inputs = (const int*)d_in[18];

    // workspace layout (all chunks 256B-aligned)
    char* ws = (char*)d_ws;
    float* qws  = (float*)ws; ws += (size_t)BB*4*DV*4;        // 1 MB
    float* ve   = (float*)ws; ws += (size_t)BB*HH*4;          // 128 KB
    float* se   = (float*)ws; ws += 512;
    float* xws  = (float*)ws; ws += (size_t)BB*DV*4;          // 256 KB
    __bf16* Pn1h = (__bf16*)ws; ws += (size_t)DF*HH*2;        // 256 KB
    __bf16* Pn1l = (__bf16*)ws; ws += (size_t)DF*HH*2;
    __bf16* Pn2h = (__bf16*)ws; ws += (size_t)HH*DV*2;
    __bf16* Pn2l = (__bf16*)ws; ws += (size_t)HH*DV*2;
    __bf16* Pqh  = (__bf16*)ws; ws += (size_t)DV*DV*2;        // 512 KB
    __bf16* Pql  = (__bf16*)ws; ws += (size_t)DV*DV*2;
    __bf16* Pc1h = (__bf16*)ws; ws += (size_t)DV*HH*2;
    __bf16* Pc1l = (__bf16*)ws; ws += (size_t)DV*HH*2;
    __bf16* Peh  = (__bf16*)ws; ws += (size_t)DE*HH*2;        // 128 KB
    __bf16* Pc2h = (__bf16*)ws; ws += (size_t)HH*32*2;        // 16 KB
    __bf16* Pc2l = (__bf16*)ws; ws += (size_t)HH*32*2;        // 16 KB
    float* nf   = (float*)ws; ws += (size_t)BB*NN*DV*4;       // 9 MB
    float* weit = (float*)ws; ws += (size_t)BB*NE*4;          // 648 KB

    k_pack_all<<<356, 256, 0, stream>>>(W_n1, W_n2, W_q, W_c1, W_e1, W_c2,
                                        Pn1h, Pn1l, Pn2h, Pn2l, Pqh, Pql, Pc1h, Pc1l,
                                        Peh, Pc2h, Pc2l);
    k_prep<<<BB, 256, 0, stream>>>(word_emb, program_inputs, W_e2, b_e2, qws, ve, se);
    k_node<<<(BB*NN)/16, 256, 0, stream>>>(node_feats, Pn1h, Pn1l, b_n1, Pn2h, Pn2l, b_n2, nf);
    k_edge<<<BB*27, 256, 0, stream>>>(edge_feats, Peh, b_e1, ve, se, weit);
    k_attn<<<BB, 256, 0, stream>>>(nf, qws, weit, xws);
    k_head<<<BB/16, 256, 0, stream>>>(xws, Pqh, Pql, b_q, Pc1h, Pc1l, b_c1,
                                      Pc2h, Pc2l, b_c2, (float*)d_out);
}

// Round 5
// 469.076 us; speedup vs baseline: 1.1295x; 1.1295x over previous
//
#include <hip/hip_runtime.h>
#include <math.h>

// Dims (CLEVR-scale, fixed)
#define BB 128
#define NN 36
#define DF 512
#define DE 256
#define DV 512
#define HH 256
#define NCC 28
#define LQ 5
#define NE 1296           // N*N edges per batch
#define SCALE 0.04419417382415922f   // 1/sqrt(512)

typedef __bf16 bf16_8 __attribute__((ext_vector_type(8)));
typedef __bf16 bf16_4 __attribute__((ext_vector_type(4)));
typedef float  f32_4  __attribute__((ext_vector_type(4)));

__device__ __forceinline__ float sigmoidf_(float x){ return 1.0f/(1.0f + expf(-x)); }
__device__ __forceinline__ float reluf_(float x){ return x > 0.f ? x : 0.f; }

__device__ __forceinline__ bf16_8 cvt8(f32_4 f0, f32_4 f1){
    bf16_8 v;
    #pragma unroll
    for (int i=0;i<4;i++){ v[i] = (__bf16)f0[i]; v[i+4] = (__bf16)f1[i]; }
    return v;
}
// hi/lo split of 8 fp32 into two bf16_8 (3-term split-bf16 emulation, ~2^-18 rel err)
__device__ __forceinline__ void split8(f32_4 f0, f32_4 f1, bf16_8& h, bf16_8& l){
    #pragma unroll
    for (int i=0;i<4;i++){
        __bf16 hi = (__bf16)f0[i];
        h[i] = hi; l[i] = (__bf16)(f0[i] - (float)hi);
        __bf16 hi2 = (__bf16)f1[i];
        h[i+4] = hi2; l[i+4] = (__bf16)(f1[i] - (float)hi2);
    }
}

// async global->LDS DMA, 16B/lane. lds_base must be wave-uniform; HW writes
// lds_base + lane*16 from per-lane gptr (use lane-contiguous gptr = coalesced).
__device__ __forceinline__ void async_copy16(const float* g, float* lds_base){
    __builtin_amdgcn_global_load_lds(
        (const __attribute__((address_space(1))) void*)g,
        (__attribute__((address_space(3))) void*)lds_base, 16, 0, 0);
}

// ---------------------------------------------------------------------------
// Pack all weight matrices into MFMA B-fragment planes.
// Blocks: [0,64) W_n1(512x256) | [64,128) W_n2(256x512) | [128,256) W_q(512x512)
//         [256,320) W_c1(512x256) | [320,352) W_e1(256x256, hi only)
//         [352,356) W_c2(256x28 -> padded N=32)
// ---------------------------------------------------------------------------
__global__ __launch_bounds__(256) void k_pack_all(
    const float* __restrict__ W_n1, const float* __restrict__ W_n2,
    const float* __restrict__ W_q,  const float* __restrict__ W_c1,
    const float* __restrict__ W_e1, const float* __restrict__ W_c2,
    __bf16* __restrict__ Pn1h, __bf16* __restrict__ Pn1l,
    __bf16* __restrict__ Pn2h, __bf16* __restrict__ Pn2l,
    __bf16* __restrict__ Pqh,  __bf16* __restrict__ Pql,
    __bf16* __restrict__ Pc1h, __bf16* __restrict__ Pc1l,
    __bf16* __restrict__ Peh,
    __bf16* __restrict__ Pc2h, __bf16* __restrict__ Pc2l)
{
    int bid = blockIdx.x;
    const float* W; __bf16 *Ph, *Pl; int N, base, realN;
    if (bid < 64)       { W=W_n1; Ph=Pn1h; Pl=Pn1l; N=256; base=0;   realN=256; }
    else if (bid < 128) { W=W_n2; Ph=Pn2h; Pl=Pn2l; N=512; base=64;  realN=512; }
    else if (bid < 256) { W=W_q;  Ph=Pqh;  Pl=Pql;  N=512; base=128; realN=512; }
    else if (bid < 320) { W=W_c1; Ph=Pc1h; Pl=Pc1l; N=256; base=256; realN=256; }
    else if (bid < 352) { W=W_e1; Ph=Peh;  Pl=nullptr; N=256; base=320; realN=256; }
    else                { W=W_c2; Ph=Pc2h; Pl=Pc2l; N=32;  base=352; realN=28;  }
    int g = (bid-base)*256 + threadIdx.x;
    int lane = g & 63, slot = g >> 6;
    int NT = N >> 4;
    int nt = slot % NT, kt = slot / NT;
    int krow = kt*32 + (lane>>4)*8, ncol = nt*16 + (lane&15);
    #pragma unroll
    for (int j=0;j<8;j++){
        float w = (ncol < realN) ? W[(size_t)(krow+j)*realN + ncol] : 0.f;
        __bf16 hi = (__bf16)w;
        Ph[(size_t)g*8+j] = hi;
        if (Pl) Pl[(size_t)g*8+j] = (__bf16)(w - (float)hi);
    }
}

// ---------------------------------------------------------------------------
// K1: per-batch: gather q0..q3; ve[b][h] = W_e2[h,:]·q2 (wave-coalesced); se[b]=b_e2·q2
// ---------------------------------------------------------------------------
__global__ __launch_bounds__(256) void k_prep(
    const float* __restrict__ word_emb, const int* __restrict__ program_inputs,
    const float* __restrict__ W_e2, const float* __restrict__ b_e2,
    float* __restrict__ qws, float* __restrict__ ve, float* __restrict__ se)
{
    int b = blockIdx.x, t = threadIdx.x, wv = t>>6, lane = t&63;
    int idx[4];
    #pragma unroll
    for (int k=0;k<4;k++) idx[k] = program_inputs[b*LQ + k];
    #pragma unroll
    for (int k=0;k<4;k++){
        qws[((size_t)(b*4+k))*DV + t]       = word_emb[(size_t)idx[k]*DV + t];
        qws[((size_t)(b*4+k))*DV + t + 256] = word_emb[(size_t)idx[k]*DV + t + 256];
    }
    const float* q2p = word_emb + (size_t)idx[2]*DV + lane*8;
    f32_4 qa = *(const f32_4*)q2p, qb = *(const f32_4*)(q2p+4);
    for (int i=0;i<64;i++){
        int h = wv*64 + i;
        const float* wr = W_e2 + (size_t)h*DV + lane*8;
        f32_4 a = *(const f32_4*)wr, c = *(const f32_4*)(wr+4);
        float p = a[0]*qa[0] + a[1]*qa[1] + a[2]*qa[2] + a[3]*qa[3]
                + c[0]*qb[0] + c[1]*qb[1] + c[2]*qb[2] + c[3]*qb[3];
        #pragma unroll
        for (int off=32; off; off>>=1) p += __shfl_xor(p, off, 64);
        if (lane==0) ve[b*HH + h] = p;
    }
    float pp = b_e2[t]*word_emb[(size_t)idx[2]*DV + t]
             + b_e2[t+256]*word_emb[(size_t)idx[2]*DV + t + 256];
    __shared__ float red[4];
    #pragma unroll
    for (int off=32; off; off>>=1) pp += __shfl_down(pp, off, 64);
    if ((t&63)==0) red[t>>6] = pp;
    __syncthreads();
    if (t==0) se[b] = red[0]+red[1]+red[2]+red[3];
}

// ---------------------------------------------------------------------------
// K2: fused node MLP: nf = relu(X@W1+b1)@W2+b2. 16 rows/block, 288 blocks.
// GEMM1 A staged via global_load_lds into fp32 LDS, 16B/row pad (row stride
// 516 dwords == 4 mod 32 -> uniform 8-dword/bank ds_read_b128). split8 in regs.
// ---------------------------------------------------------------------------
#define XROW 516   // 512 + 4 dwords pad
__global__ __launch_bounds__(256) void k_node(
    const float* __restrict__ X,
    const __bf16* __restrict__ W1h, const __bf16* __restrict__ W1l,
    const float* __restrict__ b1,
    const __bf16* __restrict__ W2h, const __bf16* __restrict__ W2l,
    const float* __restrict__ b2,
    float* __restrict__ nf)
{
    __shared__ __align__(16) float xs[16*XROW];   // 33 KB fp32 padded
    __shared__ __align__(16) __bf16 hh[4096];     // 8 KB, frag layout K=256
    __shared__ __align__(16) __bf16 hl[4096];     // 8 KB
    int r0 = blockIdx.x*16, t = threadIdx.x, wv = t>>6, lane = t&63;
    int m = lane&15, kc = lane>>4;
    int q = lane>>4, c = lane&15;

    // stage X[16x512]: wave wv rows wv*4..+4, 2 half-row DMAs each (1KB, coalesced)
    #pragma unroll
    for (int r=0;r<4;r++){
        int row = wv*4 + r;
        const float* src = X + (size_t)(r0+row)*DF + lane*4;
        async_copy16(src,       &xs[row*XROW + lane*4 - lane*4]);          // half 0
        async_copy16(src + 256, &xs[row*XROW + 256]);                       // half 1
    }
    __syncthreads();

    // GEMM1: hid[16x256] = relu(X @ W1 + b1). Wave wv: cols wv*64..+63.
    f32_4 zero = {0.f,0.f,0.f,0.f};
    f32_4 acc1[4];
    #pragma unroll
    for (int nt=0;nt<4;nt++) acc1[nt] = zero;
    for (int kt=0; kt<16; kt++){
        const float* ap = &xs[m*XROW + kt*32 + kc*8];
        f32_4 f0 = *(const f32_4*)ap;
        f32_4 f1 = *(const f32_4*)(ap+4);
        bf16_8 ah, al;
        split8(f0, f1, ah, al);
        #pragma unroll
        for (int nt=0;nt<4;nt++){
            size_t bo = ((size_t)(kt*16 + wv*4+nt)*64 + lane)*8;
            bf16_8 bh = *(const bf16_8*)(W1h + bo);
            bf16_8 bl = *(const bf16_8*)(W1l + bo);
            acc1[nt] = __builtin_amdgcn_mfma_f32_16x16x32_bf16(ah, bh, acc1[nt], 0,0,0);
            acc1[nt] = __builtin_amdgcn_mfma_f32_16x16x32_bf16(al, bh, acc1[nt], 0,0,0);
            acc1[nt] = __builtin_amdgcn_mfma_f32_16x16x32_bf16(ah, bl, acc1[nt], 0,0,0);
        }
    }
    // epilogue1: relu(+b1), hi/lo -> hid frag layout (K=256)
    #pragma unroll
    for (int nt=0;nt<4;nt++){
        int col = wv*64 + nt*16 + c;
        float bias = b1[col];
        int kt2 = col>>5, j2 = col&7;
        int lbase = ((col&31)>>3)*16;
        #pragma unroll
        for (int r=0;r<4;r++){
            int row = q*4 + r;
            float v = reluf_(acc1[nt][r] + bias);
            __bf16 hi = (__bf16)v;
            int off = (kt2*64 + lbase + row)*8 + j2;
            hh[off] = hi;
            hl[off] = (__bf16)(v - (float)hi);
        }
    }
    __syncthreads();

    // GEMM2: nf[16x512] = hid @ W2 + b2. Wave wv: cols wv*128..+127.
    f32_4 acc2[8];
    #pragma unroll
    for (int nt=0;nt<8;nt++) acc2[nt] = zero;
    for (int kt=0; kt<8; kt++){
        bf16_8 ah = *(const bf16_8*)&hh[(kt*64+lane)*8];
        bf16_8 al = *(const bf16_8*)&hl[(kt*64+lane)*8];
        #pragma unroll
        for (int nt=0;nt<8;nt++){
            size_t bo = ((size_t)(kt*32 + wv*8+nt)*64 + lane)*8;
            bf16_8 bh = *(const bf16_8*)(W2h + bo);
            bf16_8 bl = *(const bf16_8*)(W2l + bo);
            acc2[nt] = __builtin_amdgcn_mfma_f32_16x16x32_bf16(ah, bh, acc2[nt], 0,0,0);
            acc2[nt] = __builtin_amdgcn_mfma_f32_16x16x32_bf16(al, bh, acc2[nt], 0,0,0);
            acc2[nt] = __builtin_amdgcn_mfma_f32_16x16x32_bf16(ah, bl, acc2[nt], 0,0,0);
        }
    }
    #pragma unroll
    for (int nt=0;nt<8;nt++){
        int col = wv*128 + nt*16 + c;
        float bias = b2[col];
        #pragma unroll
        for (int r=0;r<4;r++){
            int row = q*4 + r;
            nf[(size_t)(r0+row)*DV + col] = acc2[nt][r] + bias;
        }
    }
}

// ---------------------------------------------------------------------------
// K4: edge kernel v4. 48 edges/block. Staging via global_load_lds (1KB/row
// coalesced DMA) into fp32 LDS with 16B/row pad (stride 260 dwords == 4 mod 32
// -> uniform bank use on frag ds_read_b128). fp32->bf16 cvt at fragment read.
// ---------------------------------------------------------------------------
#define EROW 260   // 256 + 4 dwords pad
__global__ __launch_bounds__(256) void k_edge(
    const float* __restrict__ E, const __bf16* __restrict__ Wp,
    const float* __restrict__ b_e1, const float* __restrict__ ve,
    const float* __restrict__ se, float* __restrict__ weit)
{
    __shared__ __align__(16) float es[48*EROW];   // 49.9 KB
    __shared__ float red[4][48];
    int bx = blockIdx.x;
    int b = bx / 27, tile = bx % 27;
    int e0 = tile*48;
    int t = threadIdx.x, wv = t>>6, lane = t&63;
    int m = lane&15, kc = lane>>4;
    const float* Eb = E + ((size_t)b*NE + e0)*DE;

    // stage 48 rows: wave wv rows wv*12..+12, one 1KB DMA each (coalesced)
    #pragma unroll
    for (int r=0;r<12;r++){
        int row = wv*12 + r;
        async_copy16(Eb + (size_t)row*DE + lane*4, &es[row*EROW]);
    }
    __syncthreads();

    f32_4 zero = {0.f,0.f,0.f,0.f};
    f32_4 acc[3][4];
    #pragma unroll
    for (int mt=0;mt<3;mt++)
        #pragma unroll
        for (int nt=0;nt<4;nt++) acc[mt][nt] = zero;

    for (int kt=0; kt<8; kt++){
        bf16_8 af[3];
        #pragma unroll
        for (int mt=0;mt<3;mt++){
            const float* ap = &es[(mt*16 + m)*EROW + kt*32 + kc*8];
            af[mt] = cvt8(*(const f32_4*)ap, *(const f32_4*)(ap+4));
        }
        #pragma unroll
        for (int nt=0;nt<4;nt++){
            bf16_8 bfrag = *(const bf16_8*)(Wp + ((size_t)(kt*16 + (wv*4+nt))*64 + lane)*8);
            #pragma unroll
            for (int mt=0;mt<3;mt++)
                acc[mt][nt] = __builtin_amdgcn_mfma_f32_16x16x32_bf16(af[mt], bfrag, acc[mt][nt], 0,0,0);
        }
    }

    // epilogue: relu(+bias), dot with ve over this wave's 64 n-cols, reduce
    float ves[4], be[4];
    #pragma unroll
    for (int nt=0;nt<4;nt++){
        int n = wv*64 + nt*16 + m;
        ves[nt] = ve[b*HH + n];
        be[nt]  = b_e1[n];
    }
    float part[3][4];
    #pragma unroll
    for (int mt=0;mt<3;mt++)
        #pragma unroll
        for (int r=0;r<4;r++){
            float s = 0.f;
            #pragma unroll
            for (int nt=0;nt<4;nt++)
                s = fmaf(reluf_(acc[mt][nt][r] + be[nt]), ves[nt], s);
            part[mt][r] = s;
        }
    #pragma unroll
    for (int off=1; off<16; off<<=1)
        #pragma unroll
        for (int mt=0;mt<3;mt++)
            #pragma unroll
            for (int r=0;r<4;r++)
                part[mt][r] += __shfl_xor(part[mt][r], off, 64);
    if (m==0){
        int g = lane>>4;
        #pragma unroll
        for (int mt=0;mt<3;mt++)
            #pragma unroll
            for (int r=0;r<4;r++)
                red[wv][mt*16 + g*4 + r] = part[mt][r];
    }
    __syncthreads();
    if (t < 48){
        float logit = red[0][t]+red[1][t]+red[2][t]+red[3][t] + se[b];
        weit[(size_t)b*NE + e0 + t] = sigmoidf_(logit * SCALE);
    }
}

// ---------------------------------------------------------------------------
// K5a: per-batch attention chain -> x = (pooled * q0) into xws [B,DV]
// ---------------------------------------------------------------------------
__global__ __launch_bounds__(256) void k_attn(
    const float* __restrict__ nf, const float* __restrict__ qws,
    const float* __restrict__ weit, float* __restrict__ xws)
{
    int b = blockIdx.x, t = threadIdx.x;
    int wv = t>>6, lane = t&63;
    __shared__ float a1[NN], a2[NN], a3[NN];
    __shared__ float denom;
    const float* nfb = nf + (size_t)b*NN*DV;
    const float* q0 = qws + ((size_t)(b*4+0))*DV;
    const float* q1 = qws + ((size_t)(b*4+1))*DV;
    const float* q3 = qws + ((size_t)(b*4+3))*DV;

    for (int i=wv; i<NN; i+=4){
        const float* row = nfb + (size_t)i*DV + lane*8;
        const float* qq  = q3 + lane*8;
        f32_4 x0 = *(const f32_4*)row, x1 = *(const f32_4*)(row+4);
        f32_4 y0 = *(const f32_4*)qq,  y1 = *(const f32_4*)(qq+4);
        float p = x0[0]*y0[0] + x0[1]*y0[1] + x0[2]*y0[2] + x0[3]*y0[3]
                + x1[0]*y1[0] + x1[1]*y1[1] + x1[2]*y1[2] + x1[3]*y1[3];
        #pragma unroll
        for (int off=32; off; off>>=1) p += __shfl_xor(p, off, 64);
        if (lane==0) a1[i] = sigmoidf_(p*SCALE);
    }
    __syncthreads();
    if (t < NN){
        const float* wrow = weit + (size_t)b*NE;
        float s = 0.f;
        for (int i=0;i<NN;i++) s = fmaf(a1[i], wrow[i*NN + t], s);
        a2[t] = fminf(fmaxf(s, 0.f), 1.f);
    }
    __syncthreads();
    for (int i=wv; i<NN; i+=4){
        const float* row = nfb + (size_t)i*DV + lane*8;
        const float* qq  = q1 + lane*8;
        f32_4 x0 = *(const f32_4*)row, x1 = *(const f32_4*)(row+4);
        f32_4 y0 = *(const f32_4*)qq,  y1 = *(const f32_4*)(qq+4);
        float p = x0[0]*y0[0] + x0[1]*y0[1] + x0[2]*y0[2] + x0[3]*y0[3]
                + x1[0]*y1[0] + x1[1]*y1[1] + x1[2]*y1[2] + x1[3]*y1[3];
        #pragma unroll
        for (int off=32; off; off>>=1) p += __shfl_xor(p, off, 64);
        if (lane==0) a3[i] = a2[i]*sigmoidf_(p*SCALE);
    }
    __syncthreads();
    if (t==0){
        float s = 0.f;
        for (int i=0;i<NN;i++) s += a3[i];
        denom = 1.f/(s + 1e-8f);
    }
    __syncthreads();
    float p0=0.f, p1=0.f;
    for (int i=0;i<NN;i++){
        float a = a3[i]*denom;
        p0 = fmaf(a, nfb[(size_t)i*DV + t], p0);
        p1 = fmaf(a, nfb[(size_t)i*DV + t + 256], p1);
    }
    xws[(size_t)b*DV + t]       = p0*q0[t];
    xws[(size_t)b*DV + t + 256] = p1*q0[t+256];
}

// ---------------------------------------------------------------------------
// K5b: head chain: out = relu(relu(x@W_q+b_q)@W_c1+b_c1)@W_c2+b_c2
// 8 blocks x 16 rows. GEMM3 via MFMA (W_c2 packed to N=32). 48 KB LDS.
// ---------------------------------------------------------------------------
__global__ __launch_bounds__(256) void k_head(
    const float* __restrict__ xws,
    const __bf16* __restrict__ Wqh, const __bf16* __restrict__ Wql,
    const float* __restrict__ b_q,
    const __bf16* __restrict__ Wc1h, const __bf16* __restrict__ Wc1l,
    const float* __restrict__ b_c1,
    const __bf16* __restrict__ Pc2h, const __bf16* __restrict__ Pc2l,
    const float* __restrict__ b_c2,
    float* __restrict__ out)
{
    __shared__ __align__(16) __bf16 oh[8192];   // 16 KB, o frag K=512
    __shared__ __align__(16) __bf16 ol[8192];   // 16 KB
    __shared__ __align__(16) __bf16 hfh[4096];  // 8 KB, h frag K=256
    __shared__ __align__(16) __bf16 hfl[4096];  // 8 KB

    int r0 = blockIdx.x*16, t = threadIdx.x, wv = t>>6, lane = t&63;
    int m = lane&15, kc = lane>>4;
    int q = lane>>4, c = lane&15;
    f32_4 zero = {0.f,0.f,0.f,0.f};

    // GEMM1: o[16x512] = relu(x @ W_q + b_q). A direct from global (tiny).
    const float* xr = xws + (size_t)(r0+m)*DV + kc*8;
    f32_4 acc[8];
    #pragma unroll
    for (int nt=0;nt<8;nt++) acc[nt] = zero;
    for (int kt=0; kt<16; kt++){
        f32_4 f0 = *(const f32_4*)(xr + kt*32);
        f32_4 f1 = *(const f32_4*)(xr + kt*32 + 4);
        bf16_8 ah, al;
        split8(f0, f1, ah, al);
        #pragma unroll
        for (int nt=0;nt<8;nt++){
            size_t bo = ((size_t)(kt*32 + wv*8+nt)*64 + lane)*8;
            bf16_8 bh = *(const bf16_8*)(Wqh + bo);
            bf16_8 bl = *(const bf16_8*)(Wql + bo);
            acc[nt] = __builtin_amdgcn_mfma_f32_16x16x32_bf16(ah, bh, acc[nt], 0,0,0);
            acc[nt] = __builtin_amdgcn_mfma_f32_16x16x32_bf16(al, bh, acc[nt], 0,0,0);
            acc[nt] = __builtin_amdgcn_mfma_f32_16x16x32_bf16(ah, bl, acc[nt], 0,0,0);
        }
    }
    #pragma unroll
    for (int nt=0;nt<8;nt++){
        int col = wv*128 + nt*16 + c;
        float bias = b_q[col];
        int kt2 = col>>5, j2 = col&7;
        int lbase = ((col&31)>>3)*16;
        #pragma unroll
        for (int r=0;r<4;r++){
            int row = q*4 + r;
            float v = reluf_(acc[nt][r] + bias);
            __bf16 hi = (__bf16)v;
            int off = (kt2*64 + lbase + row)*8 + j2;
            oh[off] = hi;
            ol[off] = (__bf16)(v - (float)hi);
        }
    }
    __syncthreads();

    // GEMM2: h[16x256] = relu(o @ W_c1 + b_c1). Wave: 64 cols.
    f32_4 acc2[4];
    #pragma unroll
    for (int nt=0;nt<4;nt++) acc2[nt] = zero;
    for (int kt=0; kt<16; kt++){
        bf16_8 ah = *(const bf16_8*)&oh[(kt*64+lane)*8];
        bf16_8 al = *(const bf16_8*)&ol[(kt*64+lane)*8];
        #pragma unroll
        for (int nt=0;nt<4;nt++){
            size_t bo = ((size_t)(kt*16 + wv*4+nt)*64 + lane)*8;
            bf16_8 bh = *(const bf16_8*)(Wc1h + bo);
            bf16_8 bl = *(const bf16_8*)(Wc1l + bo);
            acc2[nt] = __builtin_amdgcn_mfma_f32_16x16x32_bf16(ah, bh, acc2[nt], 0,0,0);
            acc2[nt] = __builtin_amdgcn_mfma_f32_16x16x32_bf16(al, bh, acc2[nt], 0,0,0);
            acc2[nt] = __builtin_amdgcn_mfma_f32_16x16x32_bf16(ah, bl, acc2[nt], 0,0,0);
        }
    }
    // epilogue2: relu(+b_c1) -> h frag layout (K=256), hi/lo
    #pragma unroll
    for (int nt=0;nt<4;nt++){
        int col = wv*64 + nt*16 + c;
        float bias = b_c1[col];
        int kt2 = col>>5, j2 = col&7;
        int lbase = ((col&31)>>3)*16;
        #pragma unroll
        for (int r=0;r<4;r++){
            int row = q*4 + r;
            float v = reluf_(acc2[nt][r] + bias);
            __bf16 hi = (__bf16)v;
            int off = (kt2*64 + lbase + row)*8 + j2;
            hfh[off] = hi;
            hfl[off] = (__bf16)(v - (float)hi);
        }
    }
    __syncthreads();

    // GEMM3: out[16x28] = h @ W_c2 + b_c2 via MFMA (N padded to 32).
    if (wv < 2){
        f32_4 acc3 = zero;
        for (int kt=0; kt<8; kt++){
            bf16_8 ah = *(const bf16_8*)&hfh[(kt*64+lane)*8];
            bf16_8 al = *(const bf16_8*)&hfl[(kt*64+lane)*8];
            size_t bo = ((size_t)(kt*2 + wv)*64 + lane)*8;
            bf16_8 bh = *(const bf16_8*)(Pc2h + bo);
            bf16_8 bl = *(const bf16_8*)(Pc2l + bo);
            acc3 = __builtin_amdgcn_mfma_f32_16x16x32_bf16(ah, bh, acc3, 0,0,0);
            acc3 = __builtin_amdgcn_mfma_f32_16x16x32_bf16(al, bh, acc3, 0,0,0);
            acc3 = __builtin_amdgcn_mfma_f32_16x16x32_bf16(ah, bl, acc3, 0,0,0);
        }
        int col = wv*16 + c;
        if (col < NCC){
            float bias = b_c2[col];
            #pragma unroll
            for (int r=0;r<4;r++){
                int row = q*4 + r;
                out[(size_t)(r0+row)*NCC + col] = acc3[r] + bias;
            }
        }
    }
}

// ---------------------------------------------------------------------------
extern "C" void kernel_launch(void* const* d_in, const int* in_sizes, int n_in,
                              void* d_out, int out_size, void* d_ws, size_t ws_size,
                              hipStream_t stream)
{
    const float* node_feats = (const float*)d_in[0];
    const float* edge_feats = (const float*)d_in[1];
    const float* W_n1 = (const float*)d_in[2];
    const float* b_n1 = (const float*)d_in[3];
    const float* W_n2 = (const float*)d_in[4];
    const float* b_n2 = (const float*)d_in[5];
    const float* W_e1 = (const float*)d_in[6];
    const float* b_e1 = (const float*)d_in[7];
    const float* W_e2 = (const float*)d_in[8];
    const float* b_e2 = (const float*)d_in[9];
    const float* W_q  = (const float*)d_in[10];
    const float* b_q  = (const float*)d_in[11];
    const float* W_c1 = (const float*)d_in[12];
    const float* b_c1 = (const float*)d_in[13];
    const float* W_c2 = (const float*)d_in[14];
    const float* b_c2 = (const float*)d_in[15];
    const float* word_emb = (const float*)d_in[16];
    const int* program_inputs = (const int*)d_in[18];

    // workspace layout (all chunks 256B-aligned)
    char* ws = (char*)d_ws;
    float* qws  = (float*)ws; ws += (size_t)BB*4*DV*4;        // 1 MB
    float* ve   = (float*)ws; ws += (size_t)BB*HH*4;          // 128 KB
    float* se   = (float*)ws; ws += 512;
    float* xws  = (float*)ws; ws += (size_t)BB*DV*4;          // 256 KB
    __bf16* Pn1h = (__bf16*)ws; ws += (size_t)DF*HH*2;        // 256 KB
    __bf16* Pn1l = (__bf16*)ws; ws += (size_t)DF*HH*2;
    __bf16* Pn2h = (__bf16*)ws; ws += (size_t)HH*DV*2;
    __bf16* Pn2l = (__bf16*)ws; ws += (size_t)HH*DV*2;
    __bf16* Pqh  = (__bf16*)ws; ws += (size_t)DV*DV*2;        // 512 KB
    __bf16* Pql  = (__bf16*)ws; ws += (size_t)DV*DV*2;
    __bf16* Pc1h = (__bf16*)ws; ws += (size_t)DV*HH*2;
    __bf16* Pc1l = (__bf16*)ws; ws += (size_t)DV*HH*2;
    __bf16* Peh  = (__bf16*)ws; ws += (size_t)DE*HH*2;        // 128 KB
    __bf16* Pc2h = (__bf16*)ws; ws += (size_t)HH*32*2;        // 16 KB
    __bf16* Pc2l = (__bf16*)ws; ws += (size_t)HH*32*2;        // 16 KB
    float* nf   = (float*)ws; ws += (size_t)BB*NN*DV*4;       // 9 MB
    float* weit = (float*)ws; ws += (size_t)BB*NE*4;          // 648 KB

    k_pack_all<<<356, 256, 0, stream>>>(W_n1, W_n2, W_q, W_c1, W_e1, W_c2,
                                        Pn1h, Pn1l, Pn2h, Pn2l, Pqh, Pql, Pc1h, Pc1l,
                                        Peh, Pc2h, Pc2l);
    k_prep<<<BB, 256, 0, stream>>>(word_emb, program_inputs, W_e2, b_e2, qws, ve, se);
    k_node<<<(BB*NN)/16, 256, 0, stream>>>(node_feats, Pn1h, Pn1l, b_n1, Pn2h, Pn2l, b_n2, nf);
    k_edge<<<BB*27, 256, 0, stream>>>(edge_feats, Peh, b_e1, ve, se, weit);
    k_attn<<<BB, 256, 0, stream>>>(nf, qws, weit, xws);
    k_head<<<BB/16, 256, 0, stream>>>(xws, Pqh, Pql, b_q, Pc1h, Pc1l, b_c1,
                                      Pc2h, Pc2l, b_c2, (float*)d_out);
}

// Round 6
// 447.043 us; speedup vs baseline: 1.1852x; 1.0493x over previous
//
#include <hip/hip_runtime.h>
#include <math.h>

// Dims (CLEVR-scale, fixed)
#define BB 128
#define NN 36
#define DF 512
#define DE 256
#define DV 512
#define HH 256
#define NCC 28
#define LQ 5
#define NE 1296           // N*N edges per batch
#define SCALE 0.04419417382415922f   // 1/sqrt(512)

#define EDGE_BLOCKS 3456  // 128 * 27 tiles of 48 edges
#define NODE_BLOCKS 288   // 128*36/16

typedef __bf16 bf16_8 __attribute__((ext_vector_type(8)));
typedef float  f32_4  __attribute__((ext_vector_type(4)));

__device__ __forceinline__ float sigmoidf_(float x){ return 1.0f/(1.0f + expf(-x)); }
__device__ __forceinline__ float reluf_(float x){ return x > 0.f ? x : 0.f; }

__device__ __forceinline__ bf16_8 cvt8(f32_4 f0, f32_4 f1){
    bf16_8 v;
    #pragma unroll
    for (int i=0;i<4;i++){ v[i] = (__bf16)f0[i]; v[i+4] = (__bf16)f1[i]; }
    return v;
}
// hi/lo split of 8 fp32 into two bf16_8 (3-term split-bf16 emulation, ~2^-18 rel err)
__device__ __forceinline__ void split8(f32_4 f0, f32_4 f1, bf16_8& h, bf16_8& l){
    #pragma unroll
    for (int i=0;i<4;i++){
        __bf16 hi = (__bf16)f0[i];
        h[i] = hi; l[i] = (__bf16)(f0[i] - (float)hi);
        __bf16 hi2 = (__bf16)f1[i];
        h[i+4] = hi2; l[i+4] = (__bf16)(f1[i] - (float)hi2);
    }
}

// async global->LDS DMA, 16B/lane. LDS dest = lds_base + lane*16 (wave-uniform base).
__device__ __forceinline__ void async_copy16(const float* g, float* lds_base){
    __builtin_amdgcn_global_load_lds(
        (const __attribute__((address_space(1))) void*)g,
        (__attribute__((address_space(3))) void*)lds_base, 16, 0, 0);
}

#define XROW 516   // 512 + 4 dwords pad (516 mod 32 == 4 -> uniform banks on frag reads)
#define EROW 260   // 256 + 4 dwords pad

// ---------------------------------------------------------------------------
// K0: setup = pack (blocks 0..355) + prep (blocks 356..483)
// ---------------------------------------------------------------------------
__global__ __launch_bounds__(256) void k_setup(
    const float* __restrict__ W_n1, const float* __restrict__ W_n2,
    const float* __restrict__ W_q,  const float* __restrict__ W_c1,
    const float* __restrict__ W_e1, const float* __restrict__ W_c2,
    const float* __restrict__ word_emb, const int* __restrict__ program_inputs,
    const float* __restrict__ W_e2, const float* __restrict__ b_e2,
    __bf16* __restrict__ Pn1h, __bf16* __restrict__ Pn1l,
    __bf16* __restrict__ Pn2h, __bf16* __restrict__ Pn2l,
    __bf16* __restrict__ Pqh,  __bf16* __restrict__ Pql,
    __bf16* __restrict__ Pc1h, __bf16* __restrict__ Pc1l,
    __bf16* __restrict__ Peh,
    __bf16* __restrict__ Pc2h, __bf16* __restrict__ Pc2l,
    float* __restrict__ qws, float* __restrict__ ve, float* __restrict__ se)
{
    int bid = blockIdx.x;
    if (bid < 356){
        // ---- pack branch ----
        const float* W; __bf16 *Ph, *Pl; int N, base, realN;
        if (bid < 64)       { W=W_n1; Ph=Pn1h; Pl=Pn1l; N=256; base=0;   realN=256; }
        else if (bid < 128) { W=W_n2; Ph=Pn2h; Pl=Pn2l; N=512; base=64;  realN=512; }
        else if (bid < 256) { W=W_q;  Ph=Pqh;  Pl=Pql;  N=512; base=128; realN=512; }
        else if (bid < 320) { W=W_c1; Ph=Pc1h; Pl=Pc1l; N=256; base=256; realN=256; }
        else if (bid < 352) { W=W_e1; Ph=Peh;  Pl=nullptr; N=256; base=320; realN=256; }
        else                { W=W_c2; Ph=Pc2h; Pl=Pc2l; N=32;  base=352; realN=28;  }
        int g = (bid-base)*256 + threadIdx.x;
        int lane = g & 63, slot = g >> 6;
        int NT = N >> 4;
        int nt = slot % NT, kt = slot / NT;
        int krow = kt*32 + (lane>>4)*8, ncol = nt*16 + (lane&15);
        #pragma unroll
        for (int j=0;j<8;j++){
            float w = (ncol < realN) ? W[(size_t)(krow+j)*realN + ncol] : 0.f;
            __bf16 hi = (__bf16)w;
            Ph[(size_t)g*8+j] = hi;
            if (Pl) Pl[(size_t)g*8+j] = (__bf16)(w - (float)hi);
        }
    } else {
        // ---- prep branch ----
        int b = bid - 356, t = threadIdx.x, wv = t>>6, lane = t&63;
        int idx[4];
        #pragma unroll
        for (int k=0;k<4;k++) idx[k] = program_inputs[b*LQ + k];
        #pragma unroll
        for (int k=0;k<4;k++){
            qws[((size_t)(b*4+k))*DV + t]       = word_emb[(size_t)idx[k]*DV + t];
            qws[((size_t)(b*4+k))*DV + t + 256] = word_emb[(size_t)idx[k]*DV + t + 256];
        }
        const float* q2p = word_emb + (size_t)idx[2]*DV + lane*8;
        f32_4 qa = *(const f32_4*)q2p, qb = *(const f32_4*)(q2p+4);
        for (int i=0;i<64;i++){
            int h = wv*64 + i;
            const float* wr = W_e2 + (size_t)h*DV + lane*8;
            f32_4 a = *(const f32_4*)wr, c = *(const f32_4*)(wr+4);
            float p = a[0]*qa[0] + a[1]*qa[1] + a[2]*qa[2] + a[3]*qa[3]
                    + c[0]*qb[0] + c[1]*qb[1] + c[2]*qb[2] + c[3]*qb[3];
            #pragma unroll
            for (int off=32; off; off>>=1) p += __shfl_xor(p, off, 64);
            if (lane==0) ve[b*HH + h] = p;
        }
        float pp = b_e2[t]*word_emb[(size_t)idx[2]*DV + t]
                 + b_e2[t+256]*word_emb[(size_t)idx[2]*DV + t + 256];
        __shared__ float red[4];
        #pragma unroll
        for (int off=32; off; off>>=1) pp += __shfl_down(pp, off, 64);
        if ((t&63)==0) red[t>>6] = pp;
        __syncthreads();
        if (t==0) se[b] = red[0]+red[1]+red[2]+red[3];
    }
}

// ---------------------------------------------------------------------------
// K1: main = edge (blocks 0..3455) + node (blocks 3456..3743), fused so the
// MFMA-heavy node blocks co-schedule with HBM-bound edge blocks.
// Union LDS: edge 48*EROW*4 + 768 = 50688 B; node 16*XROW*4 + 16KB = 49408 B.
// ---------------------------------------------------------------------------
__device__ __forceinline__ void edge_body(
    int bx, char* smem,
    const float* __restrict__ E, const __bf16* __restrict__ Wp,
    const float* __restrict__ b_e1, const float* __restrict__ ve,
    const float* __restrict__ se, float* __restrict__ weit)
{
    float* es  = (float*)smem;                 // 48 x EROW fp32
    float* red = (float*)(smem + 48*EROW*4);   // [4][48]
    int b = bx / 27, tile = bx % 27;
    int e0 = tile*48;
    int t = threadIdx.x, wv = t>>6, lane = t&63;
    int m = lane&15, kc = lane>>4;
    const float* Eb = E + ((size_t)b*NE + e0)*DE;

    // stage 48 rows: wave wv rows wv*12..+12, one 1KB DMA each (coalesced)
    #pragma unroll
    for (int r=0;r<12;r++){
        int row = wv*12 + r;
        async_copy16(Eb + (size_t)row*DE + lane*4, &es[row*EROW]);
    }
    __syncthreads();

    f32_4 zero = {0.f,0.f,0.f,0.f};
    f32_4 acc[3][4];
    #pragma unroll
    for (int mt=0;mt<3;mt++)
        #pragma unroll
        for (int nt=0;nt<4;nt++) acc[mt][nt] = zero;

    for (int kt=0; kt<8; kt++){
        bf16_8 af[3];
        #pragma unroll
        for (int mt=0;mt<3;mt++){
            const float* ap = &es[(mt*16 + m)*EROW + kt*32 + kc*8];
            af[mt] = cvt8(*(const f32_4*)ap, *(const f32_4*)(ap+4));
        }
        #pragma unroll
        for (int nt=0;nt<4;nt++){
            bf16_8 bfrag = *(const bf16_8*)(Wp + ((size_t)(kt*16 + (wv*4+nt))*64 + lane)*8);
            #pragma unroll
            for (int mt=0;mt<3;mt++)
                acc[mt][nt] = __builtin_amdgcn_mfma_f32_16x16x32_bf16(af[mt], bfrag, acc[mt][nt], 0,0,0);
        }
    }

    float ves[4], be[4];
    #pragma unroll
    for (int nt=0;nt<4;nt++){
        int n = wv*64 + nt*16 + m;
        ves[nt] = ve[b*HH + n];
        be[nt]  = b_e1[n];
    }
    float part[3][4];
    #pragma unroll
    for (int mt=0;mt<3;mt++)
        #pragma unroll
        for (int r=0;r<4;r++){
            float s = 0.f;
            #pragma unroll
            for (int nt=0;nt<4;nt++)
                s = fmaf(reluf_(acc[mt][nt][r] + be[nt]), ves[nt], s);
            part[mt][r] = s;
        }
    #pragma unroll
    for (int off=1; off<16; off<<=1)
        #pragma unroll
        for (int mt=0;mt<3;mt++)
            #pragma unroll
            for (int r=0;r<4;r++)
                part[mt][r] += __shfl_xor(part[mt][r], off, 64);
    if (m==0){
        int g = lane>>4;
        #pragma unroll
        for (int mt=0;mt<3;mt++)
            #pragma unroll
            for (int r=0;r<4;r++)
                red[wv*48 + mt*16 + g*4 + r] = part[mt][r];
    }
    __syncthreads();
    if (t < 48){
        float logit = red[0*48+t]+red[1*48+t]+red[2*48+t]+red[3*48+t] + se[b];
        weit[(size_t)b*NE + e0 + t] = sigmoidf_(logit * SCALE);
    }
}

__device__ __forceinline__ void node_body(
    int nb, char* smem,
    const float* __restrict__ X,
    const __bf16* __restrict__ W1h, const __bf16* __restrict__ W1l,
    const float* __restrict__ b1,
    const __bf16* __restrict__ W2h, const __bf16* __restrict__ W2l,
    const float* __restrict__ b2,
    float* __restrict__ nf)
{
    float* xs  = (float*)smem;                    // 16 x XROW fp32 (33024 B)
    __bf16* hh = (__bf16*)(smem + 33024);         // 8 KB
    __bf16* hl = (__bf16*)(smem + 41216);         // 8 KB
    int r0 = nb*16, t = threadIdx.x, wv = t>>6, lane = t&63;
    int m = lane&15, kc = lane>>4;
    int q = lane>>4, c = lane&15;

    #pragma unroll
    for (int r=0;r<4;r++){
        int row = wv*4 + r;
        const float* src = X + (size_t)(r0+row)*DF + lane*4;
        async_copy16(src,       &xs[row*XROW]);
        async_copy16(src + 256, &xs[row*XROW + 256]);
    }
    __syncthreads();

    f32_4 zero = {0.f,0.f,0.f,0.f};
    f32_4 acc1[4];
    #pragma unroll
    for (int nt=0;nt<4;nt++) acc1[nt] = zero;
    for (int kt=0; kt<16; kt++){
        const float* ap = &xs[m*XROW + kt*32 + kc*8];
        f32_4 f0 = *(const f32_4*)ap;
        f32_4 f1 = *(const f32_4*)(ap+4);
        bf16_8 ah, al;
        split8(f0, f1, ah, al);
        #pragma unroll
        for (int nt=0;nt<4;nt++){
            size_t bo = ((size_t)(kt*16 + wv*4+nt)*64 + lane)*8;
            bf16_8 bh = *(const bf16_8*)(W1h + bo);
            bf16_8 bl = *(const bf16_8*)(W1l + bo);
            acc1[nt] = __builtin_amdgcn_mfma_f32_16x16x32_bf16(ah, bh, acc1[nt], 0,0,0);
            acc1[nt] = __builtin_amdgcn_mfma_f32_16x16x32_bf16(al, bh, acc1[nt], 0,0,0);
            acc1[nt] = __builtin_amdgcn_mfma_f32_16x16x32_bf16(ah, bl, acc1[nt], 0,0,0);
        }
    }
    #pragma unroll
    for (int nt=0;nt<4;nt++){
        int col = wv*64 + nt*16 + c;
        float bias = b1[col];
        int kt2 = col>>5, j2 = col&7;
        int lbase = ((col&31)>>3)*16;
        #pragma unroll
        for (int r=0;r<4;r++){
            int row = q*4 + r;
            float v = reluf_(acc1[nt][r] + bias);
            __bf16 hi = (__bf16)v;
            int off = (kt2*64 + lbase + row)*8 + j2;
            hh[off] = hi;
            hl[off] = (__bf16)(v - (float)hi);
        }
    }
    __syncthreads();

    f32_4 acc2[8];
    #pragma unroll
    for (int nt=0;nt<8;nt++) acc2[nt] = zero;
    for (int kt=0; kt<8; kt++){
        bf16_8 ah = *(const bf16_8*)&hh[(kt*64+lane)*8];
        bf16_8 al = *(const bf16_8*)&hl[(kt*64+lane)*8];
        #pragma unroll
        for (int nt=0;nt<8;nt++){
            size_t bo = ((size_t)(kt*32 + wv*8+nt)*64 + lane)*8;
            bf16_8 bh = *(const bf16_8*)(W2h + bo);
            bf16_8 bl = *(const bf16_8*)(W2l + bo);
            acc2[nt] = __builtin_amdgcn_mfma_f32_16x16x32_bf16(ah, bh, acc2[nt], 0,0,0);
            acc2[nt] = __builtin_amdgcn_mfma_f32_16x16x32_bf16(al, bh, acc2[nt], 0,0,0);
            acc2[nt] = __builtin_amdgcn_mfma_f32_16x16x32_bf16(ah, bl, acc2[nt], 0,0,0);
        }
    }
    #pragma unroll
    for (int nt=0;nt<8;nt++){
        int col = wv*128 + nt*16 + c;
        float bias = b2[col];
        #pragma unroll
        for (int r=0;r<4;r++){
            int row = q*4 + r;
            nf[(size_t)(r0+row)*DV + col] = acc2[nt][r] + bias;
        }
    }
}

__global__ __launch_bounds__(256) void k_main(
    const float* __restrict__ E, const __bf16* __restrict__ Wp,
    const float* __restrict__ b_e1, const float* __restrict__ ve,
    const float* __restrict__ se, float* __restrict__ weit,
    const float* __restrict__ X,
    const __bf16* __restrict__ W1h, const __bf16* __restrict__ W1l,
    const float* __restrict__ b1,
    const __bf16* __restrict__ W2h, const __bf16* __restrict__ W2l,
    const float* __restrict__ b2,
    float* __restrict__ nf)
{
    __shared__ __align__(16) char smem[50688];
    int bx = blockIdx.x;
    if (bx < EDGE_BLOCKS)
        edge_body(bx, smem, E, Wp, b_e1, ve, se, weit);
    else
        node_body(bx - EDGE_BLOCKS, smem, X, W1h, W1l, b1, W2h, W2l, b2, nf);
}

// ---------------------------------------------------------------------------
// K2: per-batch attention chain -> x = (pooled * q0) into xws [B,DV]
// ---------------------------------------------------------------------------
__global__ __launch_bounds__(256) void k_attn(
    const float* __restrict__ nf, const float* __restrict__ qws,
    const float* __restrict__ weit, float* __restrict__ xws)
{
    int b = blockIdx.x, t = threadIdx.x;
    int wv = t>>6, lane = t&63;
    __shared__ float a1[NN], a2[NN], a3[NN];
    __shared__ float denom;
    const float* nfb = nf + (size_t)b*NN*DV;
    const float* q0 = qws + ((size_t)(b*4+0))*DV;
    const float* q1 = qws + ((size_t)(b*4+1))*DV;
    const float* q3 = qws + ((size_t)(b*4+3))*DV;

    #pragma unroll
    for (int i=wv; i<NN; i+=4){
        const float* row = nfb + (size_t)i*DV + lane*8;
        const float* qq  = q3 + lane*8;
        f32_4 x0 = *(const f32_4*)row, x1 = *(const f32_4*)(row+4);
        f32_4 y0 = *(const f32_4*)qq,  y1 = *(const f32_4*)(qq+4);
        float p = x0[0]*y0[0] + x0[1]*y0[1] + x0[2]*y0[2] + x0[3]*y0[3]
                + x1[0]*y1[0] + x1[1]*y1[1] + x1[2]*y1[2] + x1[3]*y1[3];
        #pragma unroll
        for (int off=32; off; off>>=1) p += __shfl_xor(p, off, 64);
        if (lane==0) a1[i] = sigmoidf_(p*SCALE);
    }
    __syncthreads();
    if (t < NN){
        const float* wrow = weit + (size_t)b*NE;
        float s = 0.f;
        #pragma unroll
        for (int i=0;i<NN;i++) s = fmaf(a1[i], wrow[i*NN + t], s);
        a2[t] = fminf(fmaxf(s, 0.f), 1.f);
    }
    __syncthreads();
    #pragma unroll
    for (int i=wv; i<NN; i+=4){
        const float* row = nfb + (size_t)i*DV + lane*8;
        const float* qq  = q1 + lane*8;
        f32_4 x0 = *(const f32_4*)row, x1 = *(const f32_4*)(row+4);
        f32_4 y0 = *(const f32_4*)qq,  y1 = *(const f32_4*)(qq+4);
        float p = x0[0]*y0[0] + x0[1]*y0[1] + x0[2]*y0[2] + x0[3]*y0[3]
                + x1[0]*y1[0] + x1[1]*y1[1] + x1[2]*y1[2] + x1[3]*y1[3];
        #pragma unroll
        for (int off=32; off; off>>=1) p += __shfl_xor(p, off, 64);
        if (lane==0) a3[i] = a2[i]*sigmoidf_(p*SCALE);
    }
    __syncthreads();
    if (t==0){
        float s = 0.f;
        for (int i=0;i<NN;i++) s += a3[i];
        denom = 1.f/(s + 1e-8f);
    }
    __syncthreads();
    float p0=0.f, p1=0.f;
    #pragma unroll
    for (int i=0;i<NN;i++){
        float a = a3[i]*denom;
        p0 = fmaf(a, nfb[(size_t)i*DV + t], p0);
        p1 = fmaf(a, nfb[(size_t)i*DV + t + 256], p1);
    }
    xws[(size_t)b*DV + t]       = p0*q0[t];
    xws[(size_t)b*DV + t + 256] = p1*q0[t+256];
}

// ---------------------------------------------------------------------------
// K3: head chain: out = relu(relu(x@W_q+b_q)@W_c1+b_c1)@W_c2+b_c2
// 8 blocks x 16 rows. x staged via DMA fp32; oh/ol aliased over dead x region.
// ---------------------------------------------------------------------------
__global__ __launch_bounds__(256) void k_head(
    const float* __restrict__ xws,
    const __bf16* __restrict__ Wqh, const __bf16* __restrict__ Wql,
    const float* __restrict__ b_q,
    const __bf16* __restrict__ Wc1h, const __bf16* __restrict__ Wc1l,
    const float* __restrict__ b_c1,
    const __bf16* __restrict__ Pc2h, const __bf16* __restrict__ Pc2l,
    const float* __restrict__ b_c2,
    float* __restrict__ out)
{
    __shared__ __align__(16) char smem[49408];
    float* xs   = (float*)smem;                 // 16 x XROW fp32 (33024 B)
    __bf16* oh  = (__bf16*)smem;                // 16 KB, aliases xs (dead after GEMM1)
    __bf16* ol  = (__bf16*)(smem + 16384);      // 16 KB
    __bf16* hfh = (__bf16*)(smem + 33024);      // 8 KB
    __bf16* hfl = (__bf16*)(smem + 41216);      // 8 KB

    int r0 = blockIdx.x*16, t = threadIdx.x, wv = t>>6, lane = t&63;
    int m = lane&15, kc = lane>>4;
    int q = lane>>4, c = lane&15;
    f32_4 zero = {0.f,0.f,0.f,0.f};

    // stage x[16x512] via DMA (coalesced 1KB half-rows)
    #pragma unroll
    for (int r=0;r<4;r++){
        int row = wv*4 + r;
        const float* src = xws + (size_t)(r0+row)*DV + lane*4;
        async_copy16(src,       &xs[row*XROW]);
        async_copy16(src + 256, &xs[row*XROW + 256]);
    }
    __syncthreads();

    // GEMM1: o[16x512] = relu(x @ W_q + b_q)
    f32_4 acc[8];
    #pragma unroll
    for (int nt=0;nt<8;nt++) acc[nt] = zero;
    for (int kt=0; kt<16; kt++){
        const float* ap = &xs[m*XROW + kt*32 + kc*8];
        f32_4 f0 = *(const f32_4*)ap;
        f32_4 f1 = *(const f32_4*)(ap+4);
        bf16_8 ah, al;
        split8(f0, f1, ah, al);
        #pragma unroll
        for (int nt=0;nt<8;nt++){
            size_t bo = ((size_t)(kt*32 + wv*8+nt)*64 + lane)*8;
            bf16_8 bh = *(const bf16_8*)(Wqh + bo);
            bf16_8 bl = *(const bf16_8*)(Wql + bo);
            acc[nt] = __builtin_amdgcn_mfma_f32_16x16x32_bf16(ah, bh, acc[nt], 0,0,0);
            acc[nt] = __builtin_amdgcn_mfma_f32_16x16x32_bf16(al, bh, acc[nt], 0,0,0);
            acc[nt] = __builtin_amdgcn_mfma_f32_16x16x32_bf16(ah, bl, acc[nt], 0,0,0);
        }
    }
    __syncthreads();   // all xs reads done before oh/ol overwrite (alias)
    #pragma unroll
    for (int nt=0;nt<8;nt++){
        int col = wv*128 + nt*16 + c;
        float bias = b_q[col];
        int kt2 = col>>5, j2 = col&7;
        int lbase = ((col&31)>>3)*16;
        #pragma unroll
        for (int r=0;r<4;r++){
            int row = q*4 + r;
            float v = reluf_(acc[nt][r] + bias);
            __bf16 hi = (__bf16)v;
            int off = (kt2*64 + lbase + row)*8 + j2;
            oh[off] = hi;
            ol[off] = (__bf16)(v - (float)hi);
        }
    }
    __syncthreads();

    // GEMM2: h[16x256] = relu(o @ W_c1 + b_c1)
    f32_4 acc2[4];
    #pragma unroll
    for (int nt=0;nt<4;nt++) acc2[nt] = zero;
    for (int kt=0; kt<16; kt++){
        bf16_8 ah = *(const bf16_8*)&oh[(kt*64+lane)*8];
        bf16_8 al = *(const bf16_8*)&ol[(kt*64+lane)*8];
        #pragma unroll
        for (int nt=0;nt<4;nt++){
            size_t bo = ((size_t)(kt*16 + wv*4+nt)*64 + lane)*8;
            bf16_8 bh = *(const bf16_8*)(Wc1h + bo);
            bf16_8 bl = *(const bf16_8*)(Wc1l + bo);
            acc2[nt] = __builtin_amdgcn_mfma_f32_16x16x32_bf16(ah, bh, acc2[nt], 0,0,0);
            acc2[nt] = __builtin_amdgcn_mfma_f32_16x16x32_bf16(al, bh, acc2[nt], 0,0,0);
            acc2[nt] = __builtin_amdgcn_mfma_f32_16x16x32_bf16(ah, bl, acc2[nt], 0,0,0);
        }
    }
    #pragma unroll
    for (int nt=0;nt<4;nt++){
        int col = wv*64 + nt*16 + c;
        float bias = b_c1[col];
        int kt2 = col>>5, j2 = col&7;
        int lbase = ((col&31)>>3)*16;
        #pragma unroll
        for (int r=0;r<4;r++){
            int row = q*4 + r;
            float v = reluf_(acc2[nt][r] + bias);
            __bf16 hi = (__bf16)v;
            int off = (kt2*64 + lbase + row)*8 + j2;
            hfh[off] = hi;
            hfl[off] = (__bf16)(v - (float)hi);
        }
    }
    __syncthreads();

    // GEMM3: out[16x28] = h @ W_c2 + b_c2 via MFMA (N padded to 32)
    if (wv < 2){
        f32_4 acc3 = zero;
        for (int kt=0; kt<8; kt++){
            bf16_8 ah = *(const bf16_8*)&hfh[(kt*64+lane)*8];
            bf16_8 al = *(const bf16_8*)&hfl[(kt*64+lane)*8];
            size_t bo = ((size_t)(kt*2 + wv)*64 + lane)*8;
            bf16_8 bh = *(const bf16_8*)(Pc2h + bo);
            bf16_8 bl = *(const bf16_8*)(Pc2l + bo);
            acc3 = __builtin_amdgcn_mfma_f32_16x16x32_bf16(ah, bh, acc3, 0,0,0);
            acc3 = __builtin_amdgcn_mfma_f32_16x16x32_bf16(al, bh, acc3, 0,0,0);
            acc3 = __builtin_amdgcn_mfma_f32_16x16x32_bf16(ah, bl, acc3, 0,0,0);
        }
        int col = wv*16 + c;
        if (col < NCC){
            float bias = b_c2[col];
            #pragma unroll
            for (int r=0;r<4;r++){
                int row = q*4 + r;
                out[(size_t)(r0+row)*NCC + col] = acc3[r] + bias;
            }
        }
    }
}

// ---------------------------------------------------------------------------
extern "C" void kernel_launch(void* const* d_in, const int* in_sizes, int n_in,
                              void* d_out, int out_size, void* d_ws, size_t ws_size,
                              hipStream_t stream)
{
    const float* node_feats = (const float*)d_in[0];
    const float* edge_feats = (const float*)d_in[1];
    const float* W_n1 = (const float*)d_in[2];
    const float* b_n1 = (const float*)d_in[3];
    const float* W_n2 = (const float*)d_in[4];
    const float* b_n2 = (const float*)d_in[5];
    const float* W_e1 = (const float*)d_in[6];
    const float* b_e1 = (const float*)d_in[7];
    const float* W_e2 = (const float*)d_in[8];
    const float* b_e2 = (const float*)d_in[9];
    const float* W_q  = (const float*)d_in[10];
    const float* b_q  = (const float*)d_in[11];
    const float* W_c1 = (const float*)d_in[12];
    const float* b_c1 = (const float*)d_in[13];
    const float* W_c2 = (const float*)d_in[14];
    const float* b_c2 = (const float*)d_in[15];
    const float* word_emb = (const float*)d_in[16];
    const int* program_inputs = (const int*)d_in[18];

    // workspace layout (all chunks 256B-aligned)
    char* ws = (char*)d_ws;
    float* qws  = (float*)ws; ws += (size_t)BB*4*DV*4;        // 1 MB
    float* ve   = (float*)ws; ws += (size_t)BB*HH*4;          // 128 KB
    float* se   = (float*)ws; ws += 512;
    float* xws  = (float*)ws; ws += (size_t)BB*DV*4;          // 256 KB
    __bf16* Pn1h = (__bf16*)ws; ws += (size_t)DF*HH*2;        // 256 KB
    __bf16* Pn1l = (__bf16*)ws; ws += (size_t)DF*HH*2;
    __bf16* Pn2h = (__bf16*)ws; ws += (size_t)HH*DV*2;
    __bf16* Pn2l = (__bf16*)ws; ws += (size_t)HH*DV*2;
    __bf16* Pqh  = (__bf16*)ws; ws += (size_t)DV*DV*2;        // 512 KB
    __bf16* Pql  = (__bf16*)ws; ws += (size_t)DV*DV*2;
    __bf16* Pc1h = (__bf16*)ws; ws += (size_t)DV*HH*2;
    __bf16* Pc1l = (__bf16*)ws; ws += (size_t)DV*HH*2;
    __bf16* Peh  = (__bf16*)ws; ws += (size_t)DE*HH*2;        // 128 KB
    __bf16* Pc2h = (__bf16*)ws; ws += (size_t)HH*32*2;        // 16 KB
    __bf16* Pc2l = (__bf16*)ws; ws += (size_t)HH*32*2;        // 16 KB
    float* nf   = (float*)ws; ws += (size_t)BB*NN*DV*4;       // 9 MB
    float* weit = (float*)ws; ws += (size_t)BB*NE*4;          // 648 KB

    k_setup<<<484, 256, 0, stream>>>(W_n1, W_n2, W_q, W_c1, W_e1, W_c2,
                                     word_emb, program_inputs, W_e2, b_e2,
                                     Pn1h, Pn1l, Pn2h, Pn2l, Pqh, Pql, Pc1h, Pc1l,
                                     Peh, Pc2h, Pc2l, qws, ve, se);
    k_main<<<EDGE_BLOCKS + NODE_BLOCKS, 256, 0, stream>>>(
        edge_feats, Peh, b_e1, ve, se, weit,
        node_feats, Pn1h, Pn1l, b_n1, Pn2h, Pn2l, b_n2, nf);
    k_attn<<<BB, 256, 0, stream>>>(nf, qws, weit, xws);
    k_head<<<BB/16, 256, 0, stream>>>(xws, Pqh, Pql, b_q, Pc1h, Pc1l, b_c1,
                                      Pc2h, Pc2l, b_c2, (float*)d_out);
}